// Round 1
// baseline (379.672 us; speedup 1.0000x reference)
//
#include <hip/hip_runtime.h>
#include <math.h>

#define W 1024
#define H 768
#define PIX (W*H)          // 786432
#define NIMG 4
#define SNUM 131072
#define CHUNK 2048
#define NBLK (PIX/CHUNK)   // 384
#define MASKV (-1e-8f)

// ---------------- Sobel edge + theta + per-image max ----------------
__global__ void edge_theta_kernel(const float* __restrict__ images,
                                  float* __restrict__ theta,
                                  float* __restrict__ edge,
                                  unsigned* __restrict__ emaxb) {
    int gid = blockIdx.x * 256 + threadIdx.x;
    int i = gid / PIX;              // blocks never straddle images (PIX % 256 == 0)
    int p = gid - i * PIX;
    int y = p >> 10, x = p & (W - 1);
    const float* img = images + (size_t)i * 3 * PIX;   // channel 0
    float e = 0.f, th = 0.f;
    if (y >= 1 && y <= H - 2 && x >= 1 && x <= W - 2) {
        const float* r0 = img + (y - 1) * W + x;
        const float* r1 = r0 + W;
        const float* r2 = r1 + W;
        float a00 = r0[-1], a01 = r0[0], a02 = r0[1];
        float a10 = r1[-1],              a12 = r1[1];
        float a20 = r2[-1], a21 = r2[0], a22 = r2[1];
        float gx = (a02 - a00) + 2.f * (a12 - a10) + (a22 - a20);
        float gy = (a00 - a20) + 2.f * (a01 - a21) + (a02 - a22);
        e = sqrtf(gx * gx + gy * gy);
        th = atan2f(gy, gx);
    }
    theta[gid] = th;
    edge[gid] = e;

    __shared__ float sm[256];
    sm[threadIdx.x] = e;
    __syncthreads();
    for (int off = 128; off > 0; off >>= 1) {
        if (threadIdx.x < off) sm[threadIdx.x] = fmaxf(sm[threadIdx.x], sm[threadIdx.x + off]);
        __syncthreads();
    }
    // edge >= 0 -> float bits are monotone under unsigned compare
    if (threadIdx.x == 0) atomicMax(&emaxb[i], __float_as_uint(sm[0]));
}

// ---------------- stable compaction: pass 1, block counts ----------------
__global__ void count_kernel(const float* __restrict__ edge,
                             const float* __restrict__ targets,
                             const unsigned* __restrict__ emaxb,
                             int* __restrict__ blkE, int* __restrict__ blkV) {
    int b = blockIdx.x, i = blockIdx.y, t = threadIdx.x;
    float thr = 0.1f * __uint_as_float(emaxb[i]);
    size_t base = (size_t)i * PIX + (size_t)b * CHUNK + t * 8;
    int cE = 0, cV = 0;
#pragma unroll
    for (int k = 0; k < 8; k++) {
        cE += (edge[base + k] >= thr);
        cV += (targets[base + k] > MASKV);
    }
    __shared__ int sE[256], sV[256];
    sE[t] = cE; sV[t] = cV;
    __syncthreads();
    for (int off = 128; off > 0; off >>= 1) {
        if (t < off) { sE[t] += sE[t + off]; sV[t] += sV[t + off]; }
        __syncthreads();
    }
    if (t == 0) { blkE[i * NBLK + b] = sE[0]; blkV[i * NBLK + b] = sV[0]; }
}

// ---------------- pass 2: exclusive scan of block counts (per image) ----------------
__global__ void scan_kernel(int* __restrict__ blkE, int* __restrict__ blkV,
                            int* __restrict__ etot, int* __restrict__ vtot) {
    int i = blockIdx.x, t = threadIdx.x;   // block = 512 threads, NBLK = 384 entries
    __shared__ int sE[512], sV[512];
    int vE = (t < NBLK) ? blkE[i * NBLK + t] : 0;
    int vV = (t < NBLK) ? blkV[i * NBLK + t] : 0;
    sE[t] = vE; sV[t] = vV;
    __syncthreads();
    for (int off = 1; off < 512; off <<= 1) {
        int e = (t >= off) ? sE[t - off] : 0;
        int v = (t >= off) ? sV[t - off] : 0;
        __syncthreads();
        sE[t] += e; sV[t] += v;
        __syncthreads();
    }
    if (t < NBLK) { blkE[i * NBLK + t] = sE[t] - vE; blkV[i * NBLK + t] = sV[t] - vV; }
    if (t == NBLK - 1) { etot[i] = sE[t]; vtot[i] = sV[t]; }
}

// ---------------- pass 3: rank-preserving scatter ----------------
__global__ void scatter_kernel(const float* __restrict__ edge,
                               const float* __restrict__ targets,
                               const unsigned* __restrict__ emaxb,
                               const int* __restrict__ blkE, const int* __restrict__ blkV,
                               int* __restrict__ compE, int* __restrict__ compV) {
    int b = blockIdx.x, i = blockIdx.y, t = threadIdx.x;
    float thr = 0.1f * __uint_as_float(emaxb[i]);
    int pbase = b * CHUNK + t * 8;         // thread t owns 8 consecutive pixels -> stable
    size_t gbase = (size_t)i * PIX + pbase;
    unsigned mE = 0, mV = 0;
    int cE = 0, cV = 0;
#pragma unroll
    for (int k = 0; k < 8; k++) {
        bool be = edge[gbase + k] >= thr;
        bool bv = targets[gbase + k] > MASKV;
        mE |= (unsigned)be << k; cE += be;
        mV |= (unsigned)bv << k; cV += bv;
    }
    __shared__ int sE[256], sV[256];
    sE[t] = cE; sV[t] = cV;
    __syncthreads();
    for (int off = 1; off < 256; off <<= 1) {     // inclusive Hillis-Steele
        int e = (t >= off) ? sE[t - off] : 0;
        int v = (t >= off) ? sV[t - off] : 0;
        __syncthreads();
        sE[t] += e; sV[t] += v;
        __syncthreads();
    }
    int offE = blkE[i * NBLK + b] + sE[t] - cE;   // exclusive offset for this thread
    int offV = blkV[i * NBLK + b] + sV[t] - cV;
    int* cEp = compE + (size_t)i * PIX;
    int* cVp = compV + (size_t)i * PIX;
#pragma unroll
    for (int k = 0; k < 8; k++) {
        int p = pbase + k;
        if (mE & (1u << k)) cEp[offE++] = p;
        if (mV & (1u << k)) cVp[offV++] = p;
    }
}

// ---------------- loss ----------------
__device__ __forceinline__ void pair_acc(const float* __restrict__ inp,
                                         const float* __restrict__ tgt,
                                         int A, int B, float& eqs, float& uns) {
    float iA = inp[A], iB = inp[B];
    float tA = tgt[A], tB = tgt[B];
    float cm = ((tA > MASKV) ? 1.f : 0.f) * ((tB > MASKV) ? 1.f : 0.f);
    float ratio = (tA + 1e-6f) / (tB + 1e-6f);
    const float HIv = 1.03f;
    const float LOv = (float)(1.0 / 1.03);        // Python computes lo in f64, then f32 compare
    bool eq = (ratio < HIv) && (ratio > LOv);
    if (eq) {
        float d = iA - iB;
        eqs += d * d * cm;
    } else {
        float label = ((ratio >= HIv) ? 1.f : 0.f) + ((ratio <= LOv) ? -1.f : 0.f);
        uns += log1pf(expf((iB - iA) * label)) * cm;
    }
}

__global__ void loss_kernel(const float* __restrict__ inputs,
                            const float* __restrict__ targets,
                            const float* __restrict__ theta,
                            const int* __restrict__ compE, const int* __restrict__ compV,
                            const int* __restrict__ etot, const int* __restrict__ vtot,
                            const int* __restrict__ ra, const int* __restrict__ rd,
                            const int* __restrict__ rp,
                            double* __restrict__ acc) {
    int i = blockIdx.y;
    int s = blockIdx.x * 256 + threadIdx.x;
    const float* inp = inputs + (size_t)i * PIX;
    const float* tgt = targets + (size_t)i * PIX;
    int eT = etot[i], vT = vtot[i];
    int minlen = (eT > 0) ? eT : 1;
    int nval = (vT > 0) ? vT : 1;

    int j = ra[(size_t)i * SNUM + s] % minlen;
    int anchor = (eT > 0) ? compE[(size_t)i * PIX + j] : j;   // argsort fallback: index 0
    float th = theta[(size_t)i * PIX + anchor];
    float sv = sinf(th), cv = cosf(th);
    int row_a = anchor >> 10, col_a = anchor & (W - 1);

    int pix[4];
#pragma unroll
    for (int k = 0; k < 4; k++) {
        int r = rd[((size_t)i * 4 + k) * SNUM + s];
        float dist = ((float)r + 2.0f) * ((k < 2) ? -1.f : 1.f);
        int cc = col_a + (int)rintf(dist * cv);   // rint = round-half-even = jnp.round
        int rr = row_a + (int)rintf(dist * sv);
        cc = min(max(cc, 0), W - 1);
        rr = min(max(rr, 0), H - 1);
        pix[k] = (rr << 10) | cc;
    }

    float eqs = 0.f, uns = 0.f;
    pair_acc(inp, tgt, pix[0], pix[1], eqs, uns);
    pair_acc(inp, tgt, pix[1], pix[2], eqs, uns);
    pair_acc(inp, tgt, pix[2], pix[3], eqs, uns);

    int r0 = rp[(size_t)i * 2 * SNUM + 2 * s]     % nval;
    int r1 = rp[(size_t)i * 2 * SNUM + 2 * s + 1] % nval;
    int A = (vT > 0) ? compV[(size_t)i * PIX + r0] : r0;
    int B = (vT > 0) ? compV[(size_t)i * PIX + r1] : r1;
    pair_acc(inp, tgt, A, B, eqs, uns);

    __shared__ float sEq[256], sUn[256];
    sEq[threadIdx.x] = eqs; sUn[threadIdx.x] = uns;
    __syncthreads();
    for (int off = 128; off > 0; off >>= 1) {
        if (threadIdx.x < off) {
            sEq[threadIdx.x] += sEq[threadIdx.x + off];
            sUn[threadIdx.x] += sUn[threadIdx.x + off];
        }
        __syncthreads();
    }
    if (threadIdx.x == 0) {
        atomicAdd(&acc[0], (double)sEq[0]);
        atomicAdd(&acc[1], (double)sUn[0]);
    }
}

__global__ void final_kernel(const double* __restrict__ acc, float* __restrict__ out) {
    if (threadIdx.x == 0 && blockIdx.x == 0) {
        double denom = 4.0 * (double)SNUM;        // each mean is over 4*S pair terms
        double loss = (acc[0] / denom + acc[1] / denom) / (double)NIMG;  // ALPHA = 1
        out[0] = (float)loss;
    }
}

extern "C" void kernel_launch(void* const* d_in, const int* in_sizes, int n_in,
                              void* d_out, int out_size, void* d_ws, size_t ws_size,
                              hipStream_t stream) {
    const float* inputs  = (const float*)d_in[0];
    const float* targets = (const float*)d_in[1];
    const float* images  = (const float*)d_in[2];
    const int* ra = (const int*)d_in[3];
    const int* rd = (const int*)d_in[4];
    const int* rp = (const int*)d_in[5];
    float* out = (float*)d_out;

    char* ws = (char*)d_ws;
    double*   acc   = (double*)ws;                 // [0]=eq sum, [1]=uneq sum
    unsigned* emaxb = (unsigned*)(ws + 16);        // 4 x u32 float-bits
    int*      etot  = (int*)(ws + 32);
    int*      vtot  = (int*)(ws + 48);
    int*      blkE  = (int*)(ws + 64);             // NIMG*NBLK
    int*      blkV  = blkE + NIMG * NBLK;
    float*    theta = (float*)(ws + 16384);
    float*    edge  = theta + (size_t)NIMG * PIX;
    int*      compE = (int*)(edge + (size_t)NIMG * PIX);
    int*      compV = compE + (size_t)NIMG * PIX;
    // total: 16384 + 4 * NIMG*PIX*4 = ~50.3 MB

    hipMemsetAsync(d_ws, 0, 64, stream);           // acc, emax bits, totals
    edge_theta_kernel<<<NIMG * PIX / 256, 256, 0, stream>>>(images, theta, edge, emaxb);
    count_kernel<<<dim3(NBLK, NIMG), 256, 0, stream>>>(edge, targets, emaxb, blkE, blkV);
    scan_kernel<<<NIMG, 512, 0, stream>>>(blkE, blkV, etot, vtot);
    scatter_kernel<<<dim3(NBLK, NIMG), 256, 0, stream>>>(edge, targets, emaxb, blkE, blkV, compE, compV);
    loss_kernel<<<dim3(SNUM / 256, NIMG), 256, 0, stream>>>(inputs, targets, theta,
                                                            compE, compV, etot, vtot,
                                                            ra, rd, rp, acc);
    final_kernel<<<1, 64, 0, stream>>>(acc, out);
}

// Round 2
// 241.718 us; speedup vs baseline: 1.5707x; 1.5707x over previous
//
#include <hip/hip_runtime.h>
#include <math.h>

#define W 1024
#define H 768
#define PIX (W*H)          // 786432
#define NIMG 4
#define SNUM 131072
#define CHUNK 2048
#define NBLK (PIX/CHUNK)   // 384
#define EBLK (PIX/256)     // 3072 edge-theta blocks per image
#define LBLK (SNUM/256)    // 512 loss blocks per image
#define MASKV (-1e-8f)

// ---------------- Sobel edge + theta + per-block max (no atomics) ----------------
__global__ void edge_theta_kernel(const float* __restrict__ images,
                                  float* __restrict__ theta,
                                  float* __restrict__ edge,
                                  float* __restrict__ blockmax) {
    int gid = blockIdx.x * 256 + threadIdx.x;
    int i = gid / PIX;              // blocks never straddle images (PIX % 256 == 0)
    int p = gid - i * PIX;
    int y = p >> 10, x = p & (W - 1);
    const float* img = images + (size_t)i * 3 * PIX;   // channel 0
    float e = 0.f, th = 0.f;
    if (y >= 1 && y <= H - 2 && x >= 1 && x <= W - 2) {
        const float* r0 = img + (y - 1) * W + x;
        const float* r1 = r0 + W;
        const float* r2 = r1 + W;
        float a00 = r0[-1], a01 = r0[0], a02 = r0[1];
        float a10 = r1[-1],              a12 = r1[1];
        float a20 = r2[-1], a21 = r2[0], a22 = r2[1];
        float gx = (a02 - a00) + 2.f * (a12 - a10) + (a22 - a20);
        float gy = (a00 - a20) + 2.f * (a01 - a21) + (a02 - a22);
        e = sqrtf(gx * gx + gy * gy);
        th = atan2f(gy, gx);
    }
    theta[gid] = th;
    edge[gid] = e;

    __shared__ float sm[256];
    sm[threadIdx.x] = e;
    __syncthreads();
    for (int off = 128; off > 0; off >>= 1) {
        if (threadIdx.x < off) sm[threadIdx.x] = fmaxf(sm[threadIdx.x], sm[threadIdx.x + off]);
        __syncthreads();
    }
    if (threadIdx.x == 0) blockmax[blockIdx.x] = sm[0];   // plain store, no contention
}

// ---------------- reduce per-block maxes -> emax[i] ----------------
__global__ void emax_reduce_kernel(const float* __restrict__ blockmax,
                                   float* __restrict__ emax) {
    int i = blockIdx.x, t = threadIdx.x;   // 1024 threads, 3072 entries per image
    const float* bm = blockmax + (size_t)i * EBLK;
    float m = fmaxf(fmaxf(bm[t], bm[t + 1024]), bm[t + 2048]);
    __shared__ float sm[1024];
    sm[t] = m;
    __syncthreads();
    for (int off = 512; off > 0; off >>= 1) {
        if (t < off) sm[t] = fmaxf(sm[t], sm[t + off]);
        __syncthreads();
    }
    if (t == 0) emax[i] = sm[0];
}

// ---------------- stable compaction: pass 1, block counts ----------------
__global__ void count_kernel(const float* __restrict__ edge,
                             const float* __restrict__ targets,
                             const float* __restrict__ emax,
                             int* __restrict__ blkE, int* __restrict__ blkV) {
    int b = blockIdx.x, i = blockIdx.y, t = threadIdx.x;
    float thr = 0.1f * emax[i];
    size_t base = (size_t)i * PIX + (size_t)b * CHUNK + t * 8;
    int cE = 0, cV = 0;
#pragma unroll
    for (int k = 0; k < 8; k++) {
        cE += (edge[base + k] >= thr);
        cV += (targets[base + k] > MASKV);
    }
    __shared__ int sE[256], sV[256];
    sE[t] = cE; sV[t] = cV;
    __syncthreads();
    for (int off = 128; off > 0; off >>= 1) {
        if (t < off) { sE[t] += sE[t + off]; sV[t] += sV[t + off]; }
        __syncthreads();
    }
    if (t == 0) { blkE[i * NBLK + b] = sE[0]; blkV[i * NBLK + b] = sV[0]; }
}

// ---------------- pass 2: exclusive scan of block counts (per image) ----------------
__global__ void scan_kernel(int* __restrict__ blkE, int* __restrict__ blkV,
                            int* __restrict__ etot, int* __restrict__ vtot) {
    int i = blockIdx.x, t = threadIdx.x;   // block = 512 threads, NBLK = 384 entries
    __shared__ int sE[512], sV[512];
    int vE = (t < NBLK) ? blkE[i * NBLK + t] : 0;
    int vV = (t < NBLK) ? blkV[i * NBLK + t] : 0;
    sE[t] = vE; sV[t] = vV;
    __syncthreads();
    for (int off = 1; off < 512; off <<= 1) {
        int e = (t >= off) ? sE[t - off] : 0;
        int v = (t >= off) ? sV[t - off] : 0;
        __syncthreads();
        sE[t] += e; sV[t] += v;
        __syncthreads();
    }
    if (t < NBLK) { blkE[i * NBLK + t] = sE[t] - vE; blkV[i * NBLK + t] = sV[t] - vV; }
    if (t == NBLK - 1) { etot[i] = sE[t]; vtot[i] = sV[t]; }
}

// ---------------- pass 3: rank-preserving scatter ----------------
__global__ void scatter_kernel(const float* __restrict__ edge,
                               const float* __restrict__ targets,
                               const float* __restrict__ emax,
                               const int* __restrict__ blkE, const int* __restrict__ blkV,
                               int* __restrict__ compE, int* __restrict__ compV) {
    int b = blockIdx.x, i = blockIdx.y, t = threadIdx.x;
    float thr = 0.1f * emax[i];
    int pbase = b * CHUNK + t * 8;         // thread t owns 8 consecutive pixels -> stable
    size_t gbase = (size_t)i * PIX + pbase;
    unsigned mE = 0, mV = 0;
    int cE = 0, cV = 0;
#pragma unroll
    for (int k = 0; k < 8; k++) {
        bool be = edge[gbase + k] >= thr;
        bool bv = targets[gbase + k] > MASKV;
        mE |= (unsigned)be << k; cE += be;
        mV |= (unsigned)bv << k; cV += bv;
    }
    __shared__ int sE[256], sV[256];
    sE[t] = cE; sV[t] = cV;
    __syncthreads();
    for (int off = 1; off < 256; off <<= 1) {     // inclusive Hillis-Steele
        int e = (t >= off) ? sE[t - off] : 0;
        int v = (t >= off) ? sV[t - off] : 0;
        __syncthreads();
        sE[t] += e; sV[t] += v;
        __syncthreads();
    }
    int offE = blkE[i * NBLK + b] + sE[t] - cE;   // exclusive offset for this thread
    int offV = blkV[i * NBLK + b] + sV[t] - cV;
    int* cEp = compE + (size_t)i * PIX;
    int* cVp = compV + (size_t)i * PIX;
#pragma unroll
    for (int k = 0; k < 8; k++) {
        int p = pbase + k;
        if (mE & (1u << k)) cEp[offE++] = p;
        if (mV & (1u << k)) cVp[offV++] = p;
    }
}

// ---------------- loss ----------------
__device__ __forceinline__ void pair_acc(const float* __restrict__ inp,
                                         const float* __restrict__ tgt,
                                         int A, int B, float& eqs, float& uns) {
    float iA = inp[A], iB = inp[B];
    float tA = tgt[A], tB = tgt[B];
    float cm = ((tA > MASKV) ? 1.f : 0.f) * ((tB > MASKV) ? 1.f : 0.f);
    float ratio = (tA + 1e-6f) / (tB + 1e-6f);
    const float HIv = 1.03f;
    const float LOv = (float)(1.0 / 1.03);        // Python computes lo in f64, then f32 compare
    bool eq = (ratio < HIv) && (ratio > LOv);
    if (eq) {
        float d = iA - iB;
        eqs += d * d * cm;
    } else {
        float label = ((ratio >= HIv) ? 1.f : 0.f) + ((ratio <= LOv) ? -1.f : 0.f);
        uns += log1pf(expf((iB - iA) * label)) * cm;
    }
}

__global__ void loss_kernel(const float* __restrict__ inputs,
                            const float* __restrict__ targets,
                            const float* __restrict__ theta,
                            const int* __restrict__ compE, const int* __restrict__ compV,
                            const int* __restrict__ etot, const int* __restrict__ vtot,
                            const int* __restrict__ ra, const int* __restrict__ rd,
                            const int* __restrict__ rp,
                            float2* __restrict__ partials) {
    int i = blockIdx.y;
    int s = blockIdx.x * 256 + threadIdx.x;
    const float* inp = inputs + (size_t)i * PIX;
    const float* tgt = targets + (size_t)i * PIX;
    int eT = etot[i], vT = vtot[i];
    int minlen = (eT > 0) ? eT : 1;
    int nval = (vT > 0) ? vT : 1;

    int j = ra[(size_t)i * SNUM + s] % minlen;
    int anchor = (eT > 0) ? compE[(size_t)i * PIX + j] : j;   // argsort fallback: index 0
    float th = theta[(size_t)i * PIX + anchor];
    float sv = sinf(th), cv = cosf(th);
    int row_a = anchor >> 10, col_a = anchor & (W - 1);

    int pix[4];
#pragma unroll
    for (int k = 0; k < 4; k++) {
        int r = rd[((size_t)i * 4 + k) * SNUM + s];
        float dist = ((float)r + 2.0f) * ((k < 2) ? -1.f : 1.f);
        int cc = col_a + (int)rintf(dist * cv);   // rint = round-half-even = jnp.round
        int rr = row_a + (int)rintf(dist * sv);
        cc = min(max(cc, 0), W - 1);
        rr = min(max(rr, 0), H - 1);
        pix[k] = (rr << 10) | cc;
    }

    float eqs = 0.f, uns = 0.f;
    pair_acc(inp, tgt, pix[0], pix[1], eqs, uns);
    pair_acc(inp, tgt, pix[1], pix[2], eqs, uns);
    pair_acc(inp, tgt, pix[2], pix[3], eqs, uns);

    int r0 = rp[(size_t)i * 2 * SNUM + 2 * s]     % nval;
    int r1 = rp[(size_t)i * 2 * SNUM + 2 * s + 1] % nval;
    int A = (vT > 0) ? compV[(size_t)i * PIX + r0] : r0;
    int B = (vT > 0) ? compV[(size_t)i * PIX + r1] : r1;
    pair_acc(inp, tgt, A, B, eqs, uns);

    __shared__ float sEq[256], sUn[256];
    sEq[threadIdx.x] = eqs; sUn[threadIdx.x] = uns;
    __syncthreads();
    for (int off = 128; off > 0; off >>= 1) {
        if (threadIdx.x < off) {
            sEq[threadIdx.x] += sEq[threadIdx.x + off];
            sUn[threadIdx.x] += sUn[threadIdx.x + off];
        }
        __syncthreads();
    }
    if (threadIdx.x == 0) {
        partials[i * LBLK + blockIdx.x] = make_float2(sEq[0], sUn[0]);  // plain store
    }
}

__global__ void final_kernel(const float2* __restrict__ partials, float* __restrict__ out) {
    int t = threadIdx.x;                       // 1024 threads, 2048 partials
    float2 a = partials[t], b = partials[t + 1024];
    double s = (double)a.x + (double)a.y + (double)b.x + (double)b.y;
    __shared__ double sm[1024];
    sm[t] = s;
    __syncthreads();
    for (int off = 512; off > 0; off >>= 1) {
        if (t < off) sm[t] += sm[t + off];
        __syncthreads();
    }
    if (t == 0) {
        double denom = 4.0 * (double)SNUM;     // each mean is over 4*S pair terms
        out[0] = (float)(sm[0] / denom / (double)NIMG);   // ALPHA = 1
    }
}

extern "C" void kernel_launch(void* const* d_in, const int* in_sizes, int n_in,
                              void* d_out, int out_size, void* d_ws, size_t ws_size,
                              hipStream_t stream) {
    const float* inputs  = (const float*)d_in[0];
    const float* targets = (const float*)d_in[1];
    const float* images  = (const float*)d_in[2];
    const int* ra = (const int*)d_in[3];
    const int* rd = (const int*)d_in[4];
    const int* rp = (const int*)d_in[5];
    float* out = (float*)d_out;

    char* ws = (char*)d_ws;
    float*    emax     = (float*)ws;                   // [4]
    int*      etot     = (int*)(ws + 16);              // [4]
    int*      vtot     = (int*)(ws + 32);              // [4]
    int*      blkE     = (int*)(ws + 64);              // NIMG*NBLK = 1536
    int*      blkV     = blkE + NIMG * NBLK;           // ends at 64+12288
    float2*   partials = (float2*)(ws + 12544);        // NIMG*LBLK = 2048 float2 = 16 KB
    float*    blockmax = (float*)(ws + 32768);         // NIMG*EBLK = 12288 floats = 48 KB
    float*    theta    = (float*)(ws + 131072);
    float*    edge     = theta + (size_t)NIMG * PIX;
    int*      compE    = (int*)(edge + (size_t)NIMG * PIX);
    int*      compV    = compE + (size_t)NIMG * PIX;
    // total: 131072 + 4*NIMG*PIX*4 = ~50.5 MB; every word written before read,
    // so the harness's 0xAA re-poison needs no memset.

    edge_theta_kernel<<<NIMG * EBLK, 256, 0, stream>>>(images, theta, edge, blockmax);
    emax_reduce_kernel<<<NIMG, 1024, 0, stream>>>(blockmax, emax);
    count_kernel<<<dim3(NBLK, NIMG), 256, 0, stream>>>(edge, targets, emax, blkE, blkV);
    scan_kernel<<<NIMG, 512, 0, stream>>>(blkE, blkV, etot, vtot);
    scatter_kernel<<<dim3(NBLK, NIMG), 256, 0, stream>>>(edge, targets, emax, blkE, blkV, compE, compV);
    loss_kernel<<<dim3(LBLK, NIMG), 256, 0, stream>>>(inputs, targets, theta,
                                                      compE, compV, etot, vtot,
                                                      ra, rd, rp, partials);
    final_kernel<<<1, 1024, 0, stream>>>(partials, out);
}